// Round 2
// baseline (688.442 us; speedup 1.0000x reference)
//
#include <hip/hip_runtime.h>
#include <hip/hip_bf16.h>

// MHA forward via split-bf16 (hi+lo) MFMA. Round 2.
// B=4, S=2048, D_MODEL=1024, H=16, D_K=64.
// a*b ~= ah*bh + ah*bl + al*bh  (3x mfma_f32_16x16x32_bf16, fp32 accumulate)
// => ~fp32 accuracy at matrix-core rate.
//
// Pipeline:
//   split x, W_q..W_o into bf16 hi/lo
//   gemm_split<1> x3  -> q,k (hi/lo, [b,h,s,dk])  and gemm_split<2> -> v transposed [b,h,dk,s]
//   flash_mfma       -> ctx (hi/lo, [b,s,1024])   (aliases X region)
//   gemm_split<0>    -> out fp32 [b,s,1024]
//
// Workspace requirement: 144 MB.

#define SEQ   2048
#define DM    1024
#define NH    16
#define DK    64
#define MTOT  8192           // B*S

typedef unsigned short u16;
typedef __attribute__((ext_vector_type(8))) short bf16x8;
typedef __attribute__((ext_vector_type(4))) float f32x4;

#define MFMA(a, b, c) __builtin_amdgcn_mfma_f32_16x16x32_bf16((a), (b), (c), 0, 0, 0)

__device__ __forceinline__ u16 f2bf(float v) {
    unsigned int x = __float_as_uint(v);
    x += 0x7fffu + ((x >> 16) & 1u);     // RNE
    return (u16)(x >> 16);
}
__device__ __forceinline__ float bf2f(u16 u) {
    return __uint_as_float(((unsigned int)u) << 16);
}

// async global->LDS, 16B per lane. LDS dest is wave-uniform base + lane*16.
__device__ __forceinline__ void gl_lds16(const void* g, void* l) {
    __builtin_amdgcn_global_load_lds((__attribute__((address_space(1))) void*)g,
                                     (__attribute__((address_space(3))) void*)l,
                                     16, 0, 0);
}

// ---------------------------------------------------------------------------
// split fp32 -> bf16 hi + bf16 lo (elementwise, float4/ushort4 vectorized)
// ---------------------------------------------------------------------------
__global__ __launch_bounds__(256) void split_f32(const float* __restrict__ src,
                                                 u16* __restrict__ dh,
                                                 u16* __restrict__ dl, int n4) {
    int i = blockIdx.x * 256 + threadIdx.x;
    if (i >= n4) return;
    float4 v = ((const float4*)src)[i];
    const float* f = (const float*)&v;
    ushort4 hh, ll;
    u16* hp = (u16*)&hh;
    u16* lp = (u16*)&ll;
#pragma unroll
    for (int j = 0; j < 4; ++j) {
        u16 h = f2bf(f[j]);
        hp[j] = h;
        lp[j] = f2bf(f[j] - bf2f(h));
    }
    ((ushort4*)dh)[i] = hh;
    ((ushort4*)dl)[i] = ll;
}

// ---------------------------------------------------------------------------
// GEMM: C[m,n] = sum_k A[m,k]*W[n,k] + bias[n], A/W given as bf16 hi/lo pairs,
// both row-major with K=1024 inner. Tile 128x128, BK=64, 256 threads (4 waves,
// 2x2 wave grid, each wave 64x64 via 4x4 frags of 16x16x32 MFMA).
// LDS tiles are chunk-XOR swizzled via the GLOBAL source address (LDS linear,
// as required by global_load_lds); frag ds_read_b128 then applies the same XOR.
// MODE 0: fp32 out row-major. MODE 1: bf16 hi/lo out [b,h,s,dk].
// MODE 2: bf16 hi/lo out [b,h,dk,s] (transposed, for V).
// ---------------------------------------------------------------------------
template <int MODE>
__global__ __launch_bounds__(256, 2) void gemm_split(
    const u16* __restrict__ Ah, const u16* __restrict__ Al,
    const u16* __restrict__ Bh, const u16* __restrict__ Bl,
    const float* __restrict__ bias,
    float* __restrict__ outF, u16* __restrict__ outH, u16* __restrict__ outL) {
    __shared__ u16 sm[4][128 * 64];   // Ahi, Alo, Bhi, Blo : 64 KB

    const int tid = threadIdx.x;
    const int w = tid >> 6, lane = tid & 63;
    const int n0 = blockIdx.x * 128, m0 = blockIdx.y * 128;
    const int wr = w >> 1, wc = w & 1;
    const int rowoff = lane >> 3;                       // 0..7
    const int cswz = ((lane & 7) ^ rowoff) << 3;        // element offset of 8-elem chunk

    const u16* src = (w == 0) ? Ah : (w == 1) ? Al : (w == 2) ? Bh : Bl;
    const int row0 = (w < 2) ? m0 : n0;
    const u16* sbase = src + (size_t)(row0 + rowoff) * 1024 + cswz;

    f32x4 acc[4][4];
#pragma unroll
    for (int a = 0; a < 4; ++a)
#pragma unroll
        for (int b = 0; b < 4; ++b) acc[a][b] = (f32x4)0.f;

    for (int k0 = 0; k0 < 1024; k0 += 64) {
#pragma unroll
        for (int i = 0; i < 16; ++i)
            gl_lds16(sbase + (size_t)(8 * i) * 1024 + k0, &sm[w][i * 512]);
        __syncthreads();   // drains vmcnt: staged tile visible
#pragma unroll
        for (int kk = 0; kk < 2; ++kk) {
            bf16x8 ah[4], al[4], bh[4], bl[4];
#pragma unroll
            for (int t = 0; t < 4; ++t) {
                const int Ra = wr * 64 + t * 16 + (lane & 15);
                const int oa = Ra * 128 + ((((kk << 2) + (lane >> 4)) ^ (Ra & 7)) << 4);
                ah[t] = *(const bf16x8*)((const char*)&sm[0][0] + oa);
                al[t] = *(const bf16x8*)((const char*)&sm[1][0] + oa);
                const int Rb = wc * 64 + t * 16 + (lane & 15);
                const int ob = Rb * 128 + ((((kk << 2) + (lane >> 4)) ^ (Rb & 7)) << 4);
                bh[t] = *(const bf16x8*)((const char*)&sm[2][0] + ob);
                bl[t] = *(const bf16x8*)((const char*)&sm[3][0] + ob);
            }
#pragma unroll
            for (int mt = 0; mt < 4; ++mt)
#pragma unroll
                for (int nt = 0; nt < 4; ++nt) {
                    acc[mt][nt] = MFMA(ah[mt], bh[nt], acc[mt][nt]);
                    acc[mt][nt] = MFMA(ah[mt], bl[nt], acc[mt][nt]);
                    acc[mt][nt] = MFMA(al[mt], bh[nt], acc[mt][nt]);
                }
        }
        __syncthreads();   // LDS reads done before next staging
    }

    // epilogue. C layout: col = lane&15, row = (lane>>4)*4 + j  (m89-verified)
#pragma unroll
    for (int mt = 0; mt < 4; ++mt) {
#pragma unroll
        for (int nt = 0; nt < 4; ++nt) {
            const int n = n0 + wc * 64 + nt * 16 + (lane & 15);
            const float bv = bias[n];
#pragma unroll
            for (int j = 0; j < 4; ++j) {
                const int m = m0 + wr * 64 + mt * 16 + (lane >> 4) * 4 + j;
                const float v = acc[mt][nt][j] + bv;
                if (MODE == 0) {
                    outF[(size_t)m * 1024 + n] = v;
                } else {
                    const u16 h16 = f2bf(v);
                    const u16 l16 = f2bf(v - bf2f(h16));
                    const int b = m >> 11, s = m & 2047, hh = n >> 6, dk = n & 63;
                    size_t idx;
                    if (MODE == 1) idx = (((size_t)(b * 16 + hh)) * 2048 + s) * 64 + dk;
                    else           idx = (((size_t)(b * 16 + hh)) * 64 + dk) * 2048 + s;
                    outH[idx] = h16;
                    outL[idx] = l16;
                }
            }
        }
    }
}

// ---------------------------------------------------------------------------
// Flash attention, split-bf16 MFMA. Block = 256 threads (4 waves), 64 q-rows
// of one (b,h); wave w owns q-rows w*16..w*16+15. KBLK=64.
// Q frags hoisted to registers (direct global 16B loads).
// K tile [64 kcol][64 dk] and V tile [64 dk][64 kcol] (from pre-transposed v)
// staged hi/lo via swizzled-source global_load_lds. Online softmax is fully
// wave-parallel (shfl_xor over the 16-lane group). P split hi/lo, staged in
// wave-private swizzled LDS, re-read as PV A-frags (no cross-wave sync).
// ---------------------------------------------------------------------------
__global__ __launch_bounds__(256, 2) void flash_mfma(
    const u16* __restrict__ Qh, const u16* __restrict__ Ql,
    const u16* __restrict__ Kh, const u16* __restrict__ Kl,
    const u16* __restrict__ Vh, const u16* __restrict__ Vl,
    const int* __restrict__ amask,
    u16* __restrict__ Ch, u16* __restrict__ Cl) {
    __shared__ u16 sK[2][64 * 64];       // 16 KB (rows = kcol)
    __shared__ u16 sV[2][64 * 64];       // 16 KB (rows = dk)
    __shared__ u16 sP[4][2][16 * 64];    // 16 KB (wave-private, rows = local q)

    const int tid = threadIdx.x, w = tid >> 6, lane = tid & 63;
    const int qt = blockIdx.x, bh = blockIdx.y;
    const int b = bh >> 4, h = bh & 15;
    const int q0 = qt * 64;
    const int rowoff = lane >> 3;
    const int cswz = ((lane & 7) ^ rowoff) << 3;
    const size_t kvbase = (size_t)bh * 2048;

    // hoist Q fragments: row = w*16 + (lane&15), k = kk*32 + (lane>>4)*8 + e
    bf16x8 qfh[2], qfl[2];
    {
        const size_t qrow = kvbase + q0 + w * 16 + (lane & 15);
        const int koff = (lane >> 4) * 8;
#pragma unroll
        for (int kk = 0; kk < 2; ++kk) {
            qfh[kk] = *(const bf16x8*)(Qh + qrow * 64 + kk * 32 + koff);
            qfl[kk] = *(const bf16x8*)(Ql + qrow * 64 + kk * 32 + koff);
        }
    }

    f32x4 o[4];
    float mi[4], li[4];
#pragma unroll
    for (int j = 0; j < 4; ++j) { mi[j] = -1e30f; li[j] = 0.f; }
#pragma unroll
    for (int d = 0; d < 4; ++d) o[d] = (f32x4)0.f;

    for (int kt = 0; kt < SEQ / 64; ++kt) {
        const int k0 = kt * 64;
        __syncthreads();   // prev iteration's K/V reads done
        {
            // wave w stages tile w: 0=Kh 1=Kl 2=Vh 3=Vl (8 chunks each)
            const u16* src = (w == 0) ? Kh : (w == 1) ? Kl : (w == 2) ? Vh : Vl;
            u16* dst = (w == 0) ? &sK[0][0] : (w == 1) ? &sK[1][0]
                     : (w == 2) ? &sV[0][0] : &sV[1][0];
            if (w < 2) {
                const u16* sb = src + (kvbase + k0 + rowoff) * 64 + cswz;
#pragma unroll
                for (int i = 0; i < 8; ++i)
                    gl_lds16(sb + (size_t)(8 * i) * 64, dst + i * 512);
            } else {
                const u16* sb = src + ((size_t)bh * 64 + rowoff) * 2048 + k0 + cswz;
#pragma unroll
                for (int i = 0; i < 8; ++i)
                    gl_lds16(sb + (size_t)(8 * i) * 2048, dst + i * 512);
            }
        }
        __syncthreads();

        // ---- S = Q K^T (16 x 64 per wave) ----
        f32x4 s[4];
#pragma unroll
        for (int nt = 0; nt < 4; ++nt) s[nt] = (f32x4)0.f;
#pragma unroll
        for (int kk = 0; kk < 2; ++kk)
#pragma unroll
            for (int nt = 0; nt < 4; ++nt) {
                const int Rb = nt * 16 + (lane & 15);
                const int ob = Rb * 128 + ((((kk << 2) + (lane >> 4)) ^ (Rb & 7)) << 4);
                bf16x8 kbh = *(const bf16x8*)((const char*)&sK[0][0] + ob);
                bf16x8 kbl = *(const bf16x8*)((const char*)&sK[1][0] + ob);
                s[nt] = MFMA(qfh[kk], kbh, s[nt]);
                s[nt] = MFMA(qfh[kk], kbl, s[nt]);
                s[nt] = MFMA(qfl[kk], kbh, s[nt]);
            }

        // ---- scale + mask ----
        int mk[4];
#pragma unroll
        for (int nt = 0; nt < 4; ++nt)
            mk[nt] = amask[b * 2048 + k0 + nt * 16 + (lane & 15)];
#pragma unroll
        for (int nt = 0; nt < 4; ++nt)
#pragma unroll
            for (int j = 0; j < 4; ++j)
                s[nt][j] = mk[nt] ? s[nt][j] * 0.125f : -1e30f;

        // ---- online softmax (rows live on 16-lane groups) ----
        float pb[4][4];
#pragma unroll
        for (int j = 0; j < 4; ++j) {
            float pm = fmaxf(fmaxf(s[0][j], s[1][j]), fmaxf(s[2][j], s[3][j]));
            pm = fmaxf(pm, __shfl_xor(pm, 1));
            pm = fmaxf(pm, __shfl_xor(pm, 2));
            pm = fmaxf(pm, __shfl_xor(pm, 4));
            pm = fmaxf(pm, __shfl_xor(pm, 8));
            const float mnew = fmaxf(mi[j], pm);
            const float sc = __expf(mi[j] - mnew);
            mi[j] = mnew;
            float rs = 0.f;
#pragma unroll
            for (int nt = 0; nt < 4; ++nt) {
                const float p = __expf(s[nt][j] - mnew);
                pb[nt][j] = p;
                rs += p;
            }
            rs += __shfl_xor(rs, 1);
            rs += __shfl_xor(rs, 2);
            rs += __shfl_xor(rs, 4);
            rs += __shfl_xor(rs, 8);
            li[j] = li[j] * sc + rs;
#pragma unroll
            for (int d = 0; d < 4; ++d) o[d][j] *= sc;
        }

        // ---- stage P (hi/lo) into wave-private swizzled LDS ----
#pragma unroll
        for (int nt = 0; nt < 4; ++nt)
#pragma unroll
            for (int j = 0; j < 4; ++j) {
                const int r = (lane >> 4) * 4 + j;
                const int c = nt * 16 + (lane & 15);
                const int ob = r * 128 + ((c * 2) ^ ((r & 7) << 4));
                const u16 ph = f2bf(pb[nt][j]);
                *(u16*)((char*)&sP[w][0][0] + ob) = ph;
                *(u16*)((char*)&sP[w][1][0] + ob) = f2bf(pb[nt][j] - bf2f(ph));
            }

        // ---- O += P V  (LDS ops of a wave are in-order: no barrier needed) ----
#pragma unroll
        for (int kkv = 0; kkv < 2; ++kkv) {
            const int Ra = lane & 15;
            const int oa = Ra * 128 + ((((kkv << 2) + (lane >> 4)) ^ (Ra & 7)) << 4);
            bf16x8 pah = *(const bf16x8*)((const char*)&sP[w][0][0] + oa);
            bf16x8 pal = *(const bf16x8*)((const char*)&sP[w][1][0] + oa);
#pragma unroll
            for (int d = 0; d < 4; ++d) {
                const int Rb = d * 16 + (lane & 15);
                const int ob = Rb * 128 + ((((kkv << 2) + (lane >> 4)) ^ (Rb & 7)) << 4);
                bf16x8 vbh = *(const bf16x8*)((const char*)&sV[0][0] + ob);
                bf16x8 vbl = *(const bf16x8*)((const char*)&sV[1][0] + ob);
                o[d] = MFMA(pah, vbh, o[d]);
                o[d] = MFMA(pah, vbl, o[d]);
                o[d] = MFMA(pal, vbh, o[d]);
            }
        }
    }

    // epilogue: normalize, write ctx (hi/lo) at [b, s, h*64+dk]
#pragma unroll
    for (int d = 0; d < 4; ++d)
#pragma unroll
        for (int j = 0; j < 4; ++j) {
            const int srow = q0 + w * 16 + (lane >> 4) * 4 + j;
            const int col = h * 64 + d * 16 + (lane & 15);
            const float v = o[d][j] / li[j];
            const u16 h16 = f2bf(v);
            const size_t idx = ((size_t)b * 2048 + srow) * 1024 + col;
            Ch[idx] = h16;
            Cl[idx] = f2bf(v - bf2f(h16));
        }
}

// ---------------------------------------------------------------------------
extern "C" void kernel_launch(void* const* d_in, const int* in_sizes, int n_in,
                              void* d_out, int out_size, void* d_ws, size_t ws_size,
                              hipStream_t stream) {
    const float* x  = (const float*)d_in[0];
    const int* am   = (const int*)d_in[1];
    const float* Wq = (const float*)d_in[2];
    const float* bq = (const float*)d_in[3];
    const float* Wk = (const float*)d_in[4];
    const float* bk = (const float*)d_in[5];
    const float* Wv = (const float*)d_in[6];
    const float* bv = (const float*)d_in[7];
    const float* Wo = (const float*)d_in[8];
    const float* bo = (const float*)d_in[9];
    float* out = (float*)d_out;

    const size_t MB = 1u << 20;
    char* ws = (char*)d_ws;
    u16* Xh  = (u16*)(ws + 0 * MB);      // 16 MB   (reused as ctx hi)
    u16* Xl  = (u16*)(ws + 16 * MB);     // 16 MB   (reused as ctx lo)
    u16* qh  = (u16*)(ws + 32 * MB);
    u16* ql  = (u16*)(ws + 48 * MB);
    u16* kh  = (u16*)(ws + 64 * MB);
    u16* kl  = (u16*)(ws + 80 * MB);
    u16* vh  = (u16*)(ws + 96 * MB);     // transposed [b,h,dk,s]
    u16* vl  = (u16*)(ws + 112 * MB);
    u16* Wqh = (u16*)(ws + 128 * MB);
    u16* Wql = (u16*)(ws + 130 * MB);
    u16* Wkh = (u16*)(ws + 132 * MB);
    u16* Wkl = (u16*)(ws + 134 * MB);
    u16* Wvh = (u16*)(ws + 136 * MB);
    u16* Wvl = (u16*)(ws + 138 * MB);
    u16* Woh = (u16*)(ws + 140 * MB);
    u16* Wol = (u16*)(ws + 142 * MB);    // total 144 MB

    // split inputs to bf16 hi/lo
    split_f32<<<(MTOT * DM / 4 + 255) / 256, 256, 0, stream>>>(x, Xh, Xl, MTOT * DM / 4);
    split_f32<<<(DM * DM / 4 + 255) / 256, 256, 0, stream>>>(Wq, Wqh, Wql, DM * DM / 4);
    split_f32<<<(DM * DM / 4 + 255) / 256, 256, 0, stream>>>(Wk, Wkh, Wkl, DM * DM / 4);
    split_f32<<<(DM * DM / 4 + 255) / 256, 256, 0, stream>>>(Wv, Wvh, Wvl, DM * DM / 4);
    split_f32<<<(DM * DM / 4 + 255) / 256, 256, 0, stream>>>(Wo, Woh, Wol, DM * DM / 4);

    dim3 ggrid(DM / 128, MTOT / 128);   // (8, 64)
    gemm_split<1><<<ggrid, 256, 0, stream>>>(Xh, Xl, Wqh, Wql, bq, nullptr, qh, ql);
    gemm_split<1><<<ggrid, 256, 0, stream>>>(Xh, Xl, Wkh, Wkl, bk, nullptr, kh, kl);
    gemm_split<2><<<ggrid, 256, 0, stream>>>(Xh, Xl, Wvh, Wvl, bv, nullptr, vh, vl);

    flash_mfma<<<dim3(SEQ / 64, 4 * NH), 256, 0, stream>>>(qh, ql, kh, kl, vh, vl, am, Xh, Xl);

    gemm_split<0><<<ggrid, 256, 0, stream>>>(Xh, Xl, Woh, Wol, bo, out, nullptr, nullptr);
}

// Round 6
// 590.617 us; speedup vs baseline: 1.1656x; 1.1656x over previous
//
#include <hip/hip_runtime.h>
#include <hip/hip_bf16.h>

// MHA forward via split-bf16 (hi+lo) MFMA. Round 6 (= round-3 kernel,
// resubmitted unchanged after three consecutive infra failures).
// B=4, S=2048, D_MODEL=1024, H=16, D_K=64.
// a*b ~= ah*bh + ah*bl + al*bh  (3x mfma_f32_16x16x32_bf16, fp32 accumulate)
//
// Flash attention: swapped operands (T12):
//   S^T = mfma(K,Q)  -> each lane owns one q-row's scores -> in-lane softmax
//   O^T = mfma(V^T,P) -> P redistributed lane-to-lane (shfl), no LDS P buffer
//   LDS 48->32 KB (4 blocks/CU), defer-max (THR=8), mask bitmask fast path.
//
// Workspace requirement: 144 MB.

#define SEQ   2048
#define DM    1024
#define NH    16
#define DK    64
#define MTOT  8192           // B*S

typedef unsigned short u16;
typedef __attribute__((ext_vector_type(8))) short bf16x8;
typedef __attribute__((ext_vector_type(4))) float f32x4;

typedef union { unsigned u[4]; bf16x8 v; } FragU;

#define MFMA(a, b, c) __builtin_amdgcn_mfma_f32_16x16x32_bf16((a), (b), (c), 0, 0, 0)

#if __has_builtin(__builtin_amdgcn_exp2f)
#define EXP2(x) __builtin_amdgcn_exp2f(x)
#else
#define EXP2(x) __expf((x) * 0.69314718056f)
#endif

__device__ __forceinline__ u16 f2bf(float v) {
    unsigned int x = __float_as_uint(v);
    x += 0x7fffu + ((x >> 16) & 1u);     // RNE
    return (u16)(x >> 16);
}
__device__ __forceinline__ float bf2f(u16 u) {
    return __uint_as_float(((unsigned int)u) << 16);
}
__device__ __forceinline__ unsigned pk2bf(float a, float b) {
    __hip_bfloat162 t = __float22bfloat162_rn(make_float2(a, b));
    unsigned r;
    __builtin_memcpy(&r, &t, 4);
    return r;
}

// async global->LDS, 16B per lane. LDS dest is wave-uniform base + lane*16.
__device__ __forceinline__ void gl_lds16(const void* g, void* l) {
    __builtin_amdgcn_global_load_lds((__attribute__((address_space(1))) void*)g,
                                     (__attribute__((address_space(3))) void*)l,
                                     16, 0, 0);
}

// ---------------------------------------------------------------------------
// split fp32 -> bf16 hi + bf16 lo (elementwise, float4/ushort4 vectorized)
// ---------------------------------------------------------------------------
__global__ __launch_bounds__(256) void split_f32(const float* __restrict__ src,
                                                 u16* __restrict__ dh,
                                                 u16* __restrict__ dl, int n4) {
    int i = blockIdx.x * 256 + threadIdx.x;
    if (i >= n4) return;
    float4 v = ((const float4*)src)[i];
    const float* f = (const float*)&v;
    ushort4 hh, ll;
    u16* hp = (u16*)&hh;
    u16* lp = (u16*)&ll;
#pragma unroll
    for (int j = 0; j < 4; ++j) {
        u16 h = f2bf(f[j]);
        hp[j] = h;
        lp[j] = f2bf(f[j] - bf2f(h));
    }
    ((ushort4*)dh)[i] = hh;
    ((ushort4*)dl)[i] = ll;
}

// ---------------------------------------------------------------------------
// GEMM (proven round 2): C[m,n] = sum_k A[m,k]*W[n,k] + bias[n].
// Tile 128x128, BK=64, 256 threads (4 waves, 2x2), 4x4 frags of 16x16x32.
// MODE 0: fp32 out row-major. MODE 1: bf16 hi/lo out [b,h,s,dk].
// MODE 2: bf16 hi/lo out [b,h,dk,s] (transposed, for V).
// ---------------------------------------------------------------------------
template <int MODE>
__global__ __launch_bounds__(256, 2) void gemm_split(
    const u16* __restrict__ Ah, const u16* __restrict__ Al,
    const u16* __restrict__ Bh, const u16* __restrict__ Bl,
    const float* __restrict__ bias,
    float* __restrict__ outF, u16* __restrict__ outH, u16* __restrict__ outL) {
    __shared__ u16 sm[4][128 * 64];   // Ahi, Alo, Bhi, Blo : 64 KB

    const int tid = threadIdx.x;
    const int w = tid >> 6, lane = tid & 63;
    const int n0 = blockIdx.x * 128, m0 = blockIdx.y * 128;
    const int wr = w >> 1, wc = w & 1;
    const int rowoff = lane >> 3;                       // 0..7
    const int cswz = ((lane & 7) ^ rowoff) << 3;        // element offset of 8-elem chunk

    const u16* src = (w == 0) ? Ah : (w == 1) ? Al : (w == 2) ? Bh : Bl;
    const int row0 = (w < 2) ? m0 : n0;
    const u16* sbase = src + (size_t)(row0 + rowoff) * 1024 + cswz;

    f32x4 acc[4][4];
#pragma unroll
    for (int a = 0; a < 4; ++a)
#pragma unroll
        for (int b = 0; b < 4; ++b) acc[a][b] = (f32x4)0.f;

    for (int k0 = 0; k0 < 1024; k0 += 64) {
#pragma unroll
        for (int i = 0; i < 16; ++i)
            gl_lds16(sbase + (size_t)(8 * i) * 1024 + k0, &sm[w][i * 512]);
        __syncthreads();   // drains vmcnt: staged tile visible
#pragma unroll
        for (int kk = 0; kk < 2; ++kk) {
            bf16x8 ah[4], al[4], bh[4], bl[4];
#pragma unroll
            for (int t = 0; t < 4; ++t) {
                const int Ra = wr * 64 + t * 16 + (lane & 15);
                const int oa = Ra * 128 + ((((kk << 2) + (lane >> 4)) ^ (Ra & 7)) << 4);
                ah[t] = *(const bf16x8*)((const char*)&sm[0][0] + oa);
                al[t] = *(const bf16x8*)((const char*)&sm[1][0] + oa);
                const int Rb = wc * 64 + t * 16 + (lane & 15);
                const int ob = Rb * 128 + ((((kk << 2) + (lane >> 4)) ^ (Rb & 7)) << 4);
                bh[t] = *(const bf16x8*)((const char*)&sm[2][0] + ob);
                bl[t] = *(const bf16x8*)((const char*)&sm[3][0] + ob);
            }
#pragma unroll
            for (int mt = 0; mt < 4; ++mt)
#pragma unroll
                for (int nt = 0; nt < 4; ++nt) {
                    acc[mt][nt] = MFMA(ah[mt], bh[nt], acc[mt][nt]);
                    acc[mt][nt] = MFMA(ah[mt], bl[nt], acc[mt][nt]);
                    acc[mt][nt] = MFMA(al[mt], bh[nt], acc[mt][nt]);
                }
        }
        __syncthreads();   // LDS reads done before next staging
    }

    // epilogue. C layout: col = lane&15, row = (lane>>4)*4 + j
#pragma unroll
    for (int mt = 0; mt < 4; ++mt) {
#pragma unroll
        for (int nt = 0; nt < 4; ++nt) {
            const int n = n0 + wc * 64 + nt * 16 + (lane & 15);
            const float bv = bias[n];
#pragma unroll
            for (int j = 0; j < 4; ++j) {
                const int m = m0 + wr * 64 + mt * 16 + (lane >> 4) * 4 + j;
                const float v = acc[mt][nt][j] + bv;
                if (MODE == 0) {
                    outF[(size_t)m * 1024 + n] = v;
                } else {
                    const u16 h16 = f2bf(v);
                    const u16 l16 = f2bf(v - bf2f(h16));
                    const int b = m >> 11, s = m & 2047, hh = n >> 6, dk = n & 63;
                    size_t idx;
                    if (MODE == 1) idx = (((size_t)(b * 16 + hh)) * 2048 + s) * 64 + dk;
                    else           idx = (((size_t)(b * 16 + hh)) * 64 + dk) * 2048 + s;
                    outH[idx] = h16;
                    outL[idx] = l16;
                }
            }
        }
    }
}

// ---------------------------------------------------------------------------
// Flash attention v2: swapped-operand MFMA, in-register softmax + P.
// Block = 256 threads (4 waves), 64 q-rows of one (b,h); wave w owns q-rows
// q0+w*16..+15 with qrow_local = lane&15. KVBLK=64.
//
// S^T = mfma(A=K-frag, B=Q-frag): s[nt][j] = S[kcol = nt*16+4*hi+j][qrow=l15]
// -> each lane holds 16 scores of ONE q-row; row reduce = in-lane tree +
//    shfl_xor(16) + shfl_xor(32).
// P packed to bf16 hi/lo pairs in-register, redistributed by shfl to the
// PV B-frag layout (col=l15, k=32*kkv+8*hi+e).
// O^T = mfma(A=V^T-frag, B=P-frag): o[ntd][j] = O[qrow][d=ntd*16+4*hi+j].
// LDS: sK 16KB + sV 16KB + 256B mask bits = 32.25 KB -> 4 blocks/CU.
// ---------------------------------------------------------------------------
__global__ __launch_bounds__(256, 4) void flash_mfma2(
    const u16* __restrict__ Qh, const u16* __restrict__ Ql,
    const u16* __restrict__ Kh, const u16* __restrict__ Kl,
    const u16* __restrict__ Vh, const u16* __restrict__ Vl,
    const int* __restrict__ amask,
    u16* __restrict__ Ch, u16* __restrict__ Cl) {
    __shared__ u16 sK[2][64 * 64];       // 16 KB (rows = kcol, cols = dk)
    __shared__ u16 sV[2][64 * 64];       // 16 KB (rows = dk, cols = kcol)
    __shared__ unsigned sMask[64];       // 2048 mask bits

    const int tid = threadIdx.x, w = tid >> 6, lane = tid & 63;
    const int qt = blockIdx.x, bh = blockIdx.y;
    const int b = bh >> 4, h = bh & 15;
    const int q0 = qt * 64;
    const int hi = lane >> 4, l15 = lane & 15;
    const int rowoff = lane >> 3;
    const int cswz = ((lane & 7) ^ rowoff) << 3;
    const size_t kvbase = (size_t)bh * 2048;
    const float CE = 0.125f * 1.44269504089f;   // scale * log2(e)

    // build mask bitmask: thread t -> byte t (kcols 8t..8t+7)
    {
        const int* ap = amask + b * 2048 + tid * 8;
        int4 a0 = *(const int4*)ap;
        int4 a1 = *(const int4*)(ap + 4);
        unsigned byte = (unsigned)(a0.x != 0) | ((unsigned)(a0.y != 0) << 1) |
                        ((unsigned)(a0.z != 0) << 2) | ((unsigned)(a0.w != 0) << 3) |
                        ((unsigned)(a1.x != 0) << 4) | ((unsigned)(a1.y != 0) << 5) |
                        ((unsigned)(a1.z != 0) << 6) | ((unsigned)(a1.w != 0) << 7);
        ((unsigned char*)sMask)[tid] = (unsigned char)byte;
    }

    // hoist Q fragments (B-frag: col=l15 -> qrow, k = 32*kk + 8*hi + e)
    bf16x8 qfh[2], qfl[2];
    {
        const size_t qrow = kvbase + q0 + w * 16 + l15;
        const int koff = hi * 8;
#pragma unroll
        for (int kk = 0; kk < 2; ++kk) {
            qfh[kk] = *(const bf16x8*)(Qh + qrow * 64 + kk * 32 + koff);
            qfl[kk] = *(const bf16x8*)(Ql + qrow * 64 + kk * 32 + koff);
        }
    }

    f32x4 o[4];
#pragma unroll
    for (int d = 0; d < 4; ++d) o[d] = (f32x4)0.f;
    float mi = -1e30f, li = 0.f;

    for (int kt = 0; kt < SEQ / 64; ++kt) {
        const int k0 = kt * 64;
        __syncthreads();   // prev iteration's LDS reads done (and mask bytes, 1st iter)
        {
            // wave w stages tile w: 0=Kh 1=Kl 2=Vh 3=Vl (8 chunks each)
            const u16* src = (w == 0) ? Kh : (w == 1) ? Kl : (w == 2) ? Vh : Vl;
            u16* dst = (w == 0) ? &sK[0][0] : (w == 1) ? &sK[1][0]
                     : (w == 2) ? &sV[0][0] : &sV[1][0];
            if (w < 2) {
                const u16* sb = src + (kvbase + k0 + rowoff) * 64 + cswz;
#pragma unroll
                for (int i = 0; i < 8; ++i)
                    gl_lds16(sb + (size_t)(8 * i) * 64, dst + i * 512);
            } else {
                const u16* sb = src + ((size_t)bh * 64 + rowoff) * 2048 + k0 + cswz;
#pragma unroll
                for (int i = 0; i < 8; ++i)
                    gl_lds16(sb + (size_t)(8 * i) * 2048, dst + i * 512);
            }
        }
        __syncthreads();

        // ---- S^T = K Q^T : s[nt][j] = S[kcol=16nt+4hi+j][qrow=l15] (raw) ----
        f32x4 s[4];
#pragma unroll
        for (int nt = 0; nt < 4; ++nt) s[nt] = (f32x4)0.f;
#pragma unroll
        for (int kk = 0; kk < 2; ++kk)
#pragma unroll
            for (int nt = 0; nt < 4; ++nt) {
                const int Rb = nt * 16 + l15;
                const int ob = Rb * 128 + ((((kk << 2) + hi) ^ (Rb & 7)) << 4);
                bf16x8 kbh = *(const bf16x8*)((const char*)&sK[0][0] + ob);
                bf16x8 kbl = *(const bf16x8*)((const char*)&sK[1][0] + ob);
                s[nt] = MFMA(kbh, qfh[kk], s[nt]);
                s[nt] = MFMA(kbh, qfl[kk], s[nt]);
                s[nt] = MFMA(kbl, qfh[kk], s[nt]);
            }

        // ---- mask (uniform all-ones fast path) ----
        const unsigned mlo = sMask[2 * kt], mhw = sMask[2 * kt + 1];
        if ((mlo & mhw) != 0xFFFFFFFFu) {
#pragma unroll
            for (int nt = 0; nt < 4; ++nt) {
                const unsigned mw = (nt & 2) ? mhw : mlo;
                const unsigned bits = mw >> (((nt & 1) << 4) + (hi << 2));
#pragma unroll
                for (int j = 0; j < 4; ++j)
                    if (!((bits >> j) & 1u)) s[nt][j] = -2e30f;
            }
        }

        // ---- online softmax, defer-max (THR = 64 raw = 8 scaled) ----
        float pm = s[0][0];
#pragma unroll
        for (int nt = 0; nt < 4; ++nt)
#pragma unroll
            for (int j = 0; j < 4; ++j) pm = fmaxf(pm, s[nt][j]);
        pm = fmaxf(pm, __shfl_xor(pm, 16));
        pm = fmaxf(pm, __shfl_xor(pm, 32));
        if (__any(pm > mi + 64.f)) {
            const float mnew = fmaxf(mi, pm);
            const float sc = EXP2((mi - mnew) * CE);
            li *= sc;
#pragma unroll
            for (int d = 0; d < 4; ++d) o[d] *= sc;
            mi = mnew;
        }
        const float nm = -mi * CE;
        float p[4][4];
        float rs = 0.f;
#pragma unroll
        for (int nt = 0; nt < 4; ++nt)
#pragma unroll
            for (int j = 0; j < 4; ++j) {
                const float e = EXP2(fmaf(s[nt][j], CE, nm));
                p[nt][j] = e;
                rs += e;
            }
        rs += __shfl_xor(rs, 16);
        rs += __shfl_xor(rs, 32);
        li += rs;

        // ---- pack P to bf16 hi/lo pairs: qph/qpl[nt][c] = kcols 16nt+4hi+2c,+1 ----
        unsigned qph[4][2], qpl[4][2];
#pragma unroll
        for (int nt = 0; nt < 4; ++nt)
#pragma unroll
            for (int c = 0; c < 2; ++c) {
                const float v0 = p[nt][2 * c], v1 = p[nt][2 * c + 1];
                const unsigned wh = pk2bf(v0, v1);
                qph[nt][c] = wh;
                const float r0 = v0 - __uint_as_float(wh << 16);
                const float r1 = v1 - __uint_as_float(wh & 0xffff0000u);
                qpl[nt][c] = pk2bf(r0, r1);
            }

        // ---- redistribute to PV B-frags and accumulate O^T ----
        // B-frag word wrd needs kcol pair (32kkv+8hi+2wrd, +1) of qrow=l15:
        //   source lane his = 2*(hi&1) + (wrd>>1), register qp[2kkv + (hi>>1)][wrd&1]
        const int src01 = l15 | ((lane & 16) << 1);   // l15 + 32*(hi&1)
        const int src23 = src01 + 16;
#pragma unroll
        for (int kkv = 0; kkv < 2; ++kkv) {
            const unsigned ah0 = __shfl(qph[2 * kkv][0], src01);
            const unsigned ah1 = __shfl(qph[2 * kkv][1], src01);
            const unsigned ah2 = __shfl(qph[2 * kkv][0], src23);
            const unsigned ah3 = __shfl(qph[2 * kkv][1], src23);
            const unsigned bh0 = __shfl(qph[2 * kkv + 1][0], src01);
            const unsigned bh1 = __shfl(qph[2 * kkv + 1][1], src01);
            const unsigned bh2 = __shfl(qph[2 * kkv + 1][0], src23);
            const unsigned bh3 = __shfl(qph[2 * kkv + 1][1], src23);
            const unsigned al0 = __shfl(qpl[2 * kkv][0], src01);
            const unsigned al1 = __shfl(qpl[2 * kkv][1], src01);
            const unsigned al2 = __shfl(qpl[2 * kkv][0], src23);
            const unsigned al3 = __shfl(qpl[2 * kkv][1], src23);
            const unsigned bl0 = __shfl(qpl[2 * kkv + 1][0], src01);
            const unsigned bl1 = __shfl(qpl[2 * kkv + 1][1], src01);
            const unsigned bl2 = __shfl(qpl[2 * kkv + 1][0], src23);
            const unsigned bl3 = __shfl(qpl[2 * kkv + 1][1], src23);
            const bool up = (hi >= 2);
            FragU uh, ul;
            uh.u[0] = up ? bh0 : ah0;
            uh.u[1] = up ? bh1 : ah1;
            uh.u[2] = up ? bh2 : ah2;
            uh.u[3] = up ? bh3 : ah3;
            ul.u[0] = up ? bl0 : al0;
            ul.u[1] = up ? bl1 : al1;
            ul.u[2] = up ? bl2 : al2;
            ul.u[3] = up ? bl3 : al3;
            const bf16x8 pbh = uh.v, pbl = ul.v;
#pragma unroll
            for (int ntd = 0; ntd < 4; ++ntd) {
                const int Rv = ntd * 16 + l15;
                const int ov = Rv * 128 + ((((kkv << 2) + hi) ^ (Rv & 7)) << 4);
                bf16x8 vbh = *(const bf16x8*)((const char*)&sV[0][0] + ov);
                bf16x8 vbl = *(const bf16x8*)((const char*)&sV[1][0] + ov);
                o[ntd] = MFMA(vbh, pbh, o[ntd]);
                o[ntd] = MFMA(vbh, pbl, o[ntd]);
                o[ntd] = MFMA(vbl, pbh, o[ntd]);
            }
        }
    }

    // ---- epilogue: normalize, packed hi/lo writes (8 B each) ----
    const float inv = 1.f / li;
    const int srow = q0 + w * 16 + l15;
    const size_t obase = ((size_t)b * 2048 + srow) * 1024 + h * 64;
#pragma unroll
    for (int ntd = 0; ntd < 4; ++ntd) {
        const float v0 = o[ntd][0] * inv, v1 = o[ntd][1] * inv;
        const float v2 = o[ntd][2] * inv, v3 = o[ntd][3] * inv;
        const unsigned wh0 = pk2bf(v0, v1), wh1 = pk2bf(v2, v3);
        const float r0 = v0 - __uint_as_float(wh0 << 16);
        const float r1 = v1 - __uint_as_float(wh0 & 0xffff0000u);
        const float r2 = v2 - __uint_as_float(wh1 << 16);
        const float r3 = v3 - __uint_as_float(wh1 & 0xffff0000u);
        const unsigned wl0 = pk2bf(r0, r1), wl1 = pk2bf(r2, r3);
        const size_t idx = obase + ntd * 16 + hi * 4;
        uint2 sh, sl;
        sh.x = wh0; sh.y = wh1;
        sl.x = wl0; sl.y = wl1;
        *(uint2*)&Ch[idx] = sh;
        *(uint2*)&Cl[idx] = sl;
    }
}

// ---------------------------------------------------------------------------
extern "C" void kernel_launch(void* const* d_in, const int* in_sizes, int n_in,
                              void* d_out, int out_size, void* d_ws, size_t ws_size,
                              hipStream_t stream) {
    const float* x  = (const float*)d_in[0];
    const int* am   = (const int*)d_in[1];
    const float* Wq = (const float*)d_in[2];
    const float* bq = (const float*)d_in[3];
    const float* Wk = (const float*)d_in[4];
    const float* bk = (const float*)d_in[5];
    const float* Wv = (const float*)d_in[6];
    const float* bv = (const float*)d_in[7];
    const float* Wo = (const float*)d_in[8];
    const float* bo = (const float*)d_in[9];
    float* out = (float*)d_out;

    const size_t MB = 1u << 20;
    char* ws = (char*)d_ws;
    u16* Xh  = (u16*)(ws + 0 * MB);      // 16 MB   (reused as ctx hi)
    u16* Xl  = (u16*)(ws + 16 * MB);     // 16 MB   (reused as ctx lo)
    u16* qh  = (u16*)(ws + 32 * MB);
    u16* ql  = (u16*)(ws + 48 * MB);
    u16* kh  = (u16*)(ws + 64 * MB);
    u16* kl  = (u16*)(ws + 80 * MB);
    u16* vh  = (u16*)(ws + 96 * MB);     // transposed [b,h,dk,s]
    u16* vl  = (u16*)(ws + 112 * MB);
    u16* Wqh = (u16*)(ws + 128 * MB);
    u16* Wql = (u16*)(ws + 130 * MB);
    u16* Wkh = (u16*)(ws + 132 * MB);
    u16* Wkl = (u16*)(ws + 134 * MB);
    u16* Wvh = (u16*)(ws + 136 * MB);
    u16* Wvl = (u16*)(ws + 138 * MB);
    u16* Woh = (u16*)(ws + 140 * MB);
    u16* Wol = (u16*)(ws + 142 * MB);    // total 144 MB

    // split inputs to bf16 hi/lo
    split_f32<<<(MTOT * DM / 4 + 255) / 256, 256, 0, stream>>>(x, Xh, Xl, MTOT * DM / 4);
    split_f32<<<(DM * DM / 4 + 255) / 256, 256, 0, stream>>>(Wq, Wqh, Wql, DM * DM / 4);
    split_f32<<<(DM * DM / 4 + 255) / 256, 256, 0, stream>>>(Wk, Wkh, Wkl, DM * DM / 4);
    split_f32<<<(DM * DM / 4 + 255) / 256, 256, 0, stream>>>(Wv, Wvh, Wvl, DM * DM / 4);
    split_f32<<<(DM * DM / 4 + 255) / 256, 256, 0, stream>>>(Wo, Woh, Wol, DM * DM / 4);

    dim3 ggrid(DM / 128, MTOT / 128);   // (8, 64)
    gemm_split<1><<<ggrid, 256, 0, stream>>>(Xh, Xl, Wqh, Wql, bq, nullptr, qh, ql);
    gemm_split<1><<<ggrid, 256, 0, stream>>>(Xh, Xl, Wkh, Wkl, bk, nullptr, kh, kl);
    gemm_split<2><<<ggrid, 256, 0, stream>>>(Xh, Xl, Wvh, Wvl, bv, nullptr, vh, vl);

    flash_mfma2<<<dim3(SEQ / 64, 4 * NH), 256, 0, stream>>>(qh, ql, kh, kl, vh, vl, am, Xh, Xl);

    gemm_split<0><<<ggrid, 256, 0, stream>>>(Xh, Xl, Woh, Wol, bo, out, nullptr, nullptr);
}